// Round 1
// baseline (399.816 us; speedup 1.0000x reference)
//
#include <hip/hip_runtime.h>
#include <hip/hip_bf16.h>

#define D 64
#define K 400

// One thread per row of x. Row held in 64 VGPRs; codebook read with
// wave-uniform addressing (scalar-load path); argmin over
// score_k = ||e_k||^2 - 2*x.e_k  (||x||^2 dropped — row-constant).
__global__ __launch_bounds__(256) void vq_argmin_gather(
    const float* __restrict__ x,
    const float* __restrict__ emb,
    float* __restrict__ out,
    int nrows) {
  __shared__ float s_norm[K];

  // Per-block codebook norms (52 MFLOP total across grid — negligible).
  for (int k = threadIdx.x; k < K; k += blockDim.x) {
    const float* e = emb + k * D;
    float s = 0.f;
#pragma unroll
    for (int d = 0; d < D; ++d) s = fmaf(e[d], e[d], s);
    s_norm[k] = s;
  }
  __syncthreads();

  int r = blockIdx.x * blockDim.x + threadIdx.x;
  if (r >= nrows) return;

  // Load this thread's row into registers (16B vector loads).
  float xr[D];
  const float4* xv = (const float4*)(x + (size_t)r * D);
#pragma unroll
  for (int j = 0; j < D / 4; ++j) {
    float4 t = xv[j];
    xr[4 * j + 0] = t.x;
    xr[4 * j + 1] = t.y;
    xr[4 * j + 2] = t.z;
    xr[4 * j + 3] = t.w;
  }

  float best = 3.4e38f;
  int bestk = 0;
  // k-loop: codebook element loads are wave-uniform -> scalar pipe.
  // Unroll 2: two independent fmac chains per thread.
#pragma unroll 2
  for (int k = 0; k < K; ++k) {
    const float* e = emb + k * D;
    float acc = 0.f;
#pragma unroll
    for (int d = 0; d < D; ++d) acc = fmaf(e[d], xr[d], acc);
    float score = fmaf(-2.f, acc, s_norm[k]);
    if (score < best) {  // strict < == first-occurrence, matches np.argmin
      best = score;
      bestk = k;
    }
  }

  // Gather winning code (emb is L1/L2-hot, 100 KB).
  float4* ov = (float4*)(out + (size_t)r * D);
  const float4* ev = (const float4*)(emb + (size_t)bestk * D);
#pragma unroll
  for (int j = 0; j < D / 4; ++j) ov[j] = ev[j];
}

extern "C" void kernel_launch(void* const* d_in, const int* in_sizes, int n_in,
                              void* d_out, int out_size, void* d_ws, size_t ws_size,
                              hipStream_t stream) {
  const float* x = (const float*)d_in[0];
  const float* emb = (const float*)d_in[1];
  float* out = (float*)d_out;
  int nrows = in_sizes[0] / D;  // 262144
  int block = 256;
  int grid = (nrows + block - 1) / block;  // 1024
  vq_argmin_gather<<<grid, block, 0, stream>>>(x, emb, out, nrows);
}

// Round 2
// 147.583 us; speedup vs baseline: 2.7091x; 2.7091x over previous
//
#include <hip/hip_runtime.h>
#include <hip/hip_bf16.h>

#define D 64
#define K 400
#define KT 25            // K/16 code tiles
#define BLOCK 1024
#define WPB (BLOCK / 64) // 16 waves per block

typedef _Float16 f16x8 __attribute__((ext_vector_type(8)));
typedef float f32x4 __attribute__((ext_vector_type(4)));

// scores = ||e||^2 - 2 x.e ; computed via f16 hi/lo split MFMA:
//   2e = eh + 2^-11 el,  x = xh + 2^-11 xl   (el, xl stored pre-scaled by 2^11)
//   dot(x,2e) ~= [xh.eh] + 2^-11 [xh.el + xl.eh]
// argmax over (dot - ||e||^2)  ==  argmin over score.
__global__ __launch_bounds__(BLOCK, 4) void vq_mfma(
    const float* __restrict__ x,
    const float* __restrict__ emb,
    float* __restrict__ out,
    int nrows) {
  // B frags in MFMA lane order: [tile][frag {c0hi,c0lo,c1hi,c1lo}][lane][8]
  __shared__ __align__(16) _Float16 sB[KT][4][64][8]; // 102,400 B
  __shared__ float s_norm[K];                         // 1,600 B

  const int tid = threadIdx.x;

  // ---- stage codebook into fragment-ordered LDS ----
  for (int e = tid; e < KT * 4 * 64; e += BLOCK) {
    int t = e >> 8;
    int f = (e >> 6) & 3;
    int l = e & 63;
    int code = t * 16 + (l & 15);
    int kb = ((l >> 4) << 3) + ((f >> 1) << 5);
    const float* ep = emb + code * D + kb;
    float v[8];
    *(float4*)&v[0] = *(const float4*)ep;
    *(float4*)&v[4] = *(const float4*)(ep + 4);
    _Float16 h[8];
    if ((f & 1) == 0) {
#pragma unroll
      for (int j = 0; j < 8; ++j) h[j] = (_Float16)(2.0f * v[j]);
    } else {
#pragma unroll
      for (int j = 0; j < 8; ++j) {
        float s = 2.0f * v[j];
        _Float16 hh = (_Float16)s;
        float r = s - (float)hh;
        h[j] = (_Float16)(r * 2048.0f); // scaled 2^11: stays normal f16
      }
    }
    *(f16x8*)&sB[t][f][l][0] = *(f16x8*)&h[0];
  }
  for (int k = tid; k < K; k += BLOCK) {
    const float* ep = emb + k * D;
    float s = 0.f;
#pragma unroll
    for (int d = 0; d < D; ++d) s = fmaf(ep[d], ep[d], s);
    s_norm[k] = s;
  }
  __syncthreads();

  const int lane = tid & 63;
  const int wid = tid >> 6;
  const int gw = blockIdx.x * WPB + wid;
  const int nw = gridDim.x * WPB;
  const int l15 = lane & 15;
  const int q = lane >> 4;

  const int npair = nrows >> 5; // 32 rows per wave-iteration
  for (int p = gw; p < npair; p += nw) {
    const int row0 = p << 5;

    // ---- load + split A fragments (16 rows x 2 tiles, regs only) ----
    f16x8 xh[2][2], xl[2][2];
#pragma unroll
    for (int a = 0; a < 2; ++a)
#pragma unroll
      for (int c = 0; c < 2; ++c) {
        const float* xp =
            x + (size_t)(row0 + a * 16 + l15) * D + q * 8 + c * 32;
        float v[8];
        *(float4*)&v[0] = *(const float4*)xp;
        *(float4*)&v[4] = *(const float4*)(xp + 4);
        _Float16 hh[8], ll[8];
#pragma unroll
        for (int j = 0; j < 8; ++j) {
          _Float16 h = (_Float16)v[j];
          float r = v[j] - (float)h;
          hh[j] = h;
          ll[j] = (_Float16)(r * 2048.0f);
        }
        xh[a][c] = *(f16x8*)&hh[0];
        xl[a][c] = *(f16x8*)&ll[0];
      }

    float bestm[2][4];
    int bestt[2][4];
#pragma unroll
    for (int a = 0; a < 2; ++a)
#pragma unroll
      for (int i = 0; i < 4; ++i) {
        bestm[a][i] = -3.4e38f;
        bestt[a][i] = 0;
      }

    // ---- 25 code tiles ----
    for (int t = 0; t < KT; ++t) {
      f16x8 bh0 = *(const f16x8*)&sB[t][0][lane][0];
      f16x8 bl0 = *(const f16x8*)&sB[t][1][lane][0];
      f16x8 bh1 = *(const f16x8*)&sB[t][2][lane][0];
      f16x8 bl1 = *(const f16x8*)&sB[t][3][lane][0];
      float nrm = s_norm[t * 16 + l15];
#pragma unroll
      for (int a = 0; a < 2; ++a) {
        f32x4 ah = {0.f, 0.f, 0.f, 0.f};
        f32x4 al = {0.f, 0.f, 0.f, 0.f};
        ah = __builtin_amdgcn_mfma_f32_16x16x32_f16(xh[a][0], bh0, ah, 0, 0, 0);
        ah = __builtin_amdgcn_mfma_f32_16x16x32_f16(xh[a][1], bh1, ah, 0, 0, 0);
        al = __builtin_amdgcn_mfma_f32_16x16x32_f16(xh[a][0], bl0, al, 0, 0, 0);
        al = __builtin_amdgcn_mfma_f32_16x16x32_f16(xl[a][0], bh0, al, 0, 0, 0);
        al = __builtin_amdgcn_mfma_f32_16x16x32_f16(xh[a][1], bl1, al, 0, 0, 0);
        al = __builtin_amdgcn_mfma_f32_16x16x32_f16(xl[a][1], bh1, al, 0, 0, 0);
#pragma unroll
        for (int i = 0; i < 4; ++i) {
          float dv = fmaf(al[i], 4.8828125e-4f, ah[i]); // + 2^-11 * cross
          float m = dv - nrm;                           // = -score
          bool gt = m > bestm[a][i];
          bestm[a][i] = gt ? m : bestm[a][i];
          bestt[a][i] = gt ? t : bestt[a][i];
        }
      }
    }

    // ---- argmin reduce across the 16 lanes of each row-group + write ----
#pragma unroll
    for (int a = 0; a < 2; ++a) {
      float bv[4];
      int bk[4];
#pragma unroll
      for (int i = 0; i < 4; ++i) {
        bv[i] = bestm[a][i];
        bk[i] = bestt[a][i] * 16 + l15;
      }
#pragma unroll
      for (int m = 1; m <= 8; m <<= 1) {
#pragma unroll
        for (int i = 0; i < 4; ++i) {
          float ov = __shfl_xor(bv[i], m, 64);
          int ok = __shfl_xor(bk[i], m, 64);
          bool take = (ov > bv[i]) || ((ov == bv[i]) && (ok < bk[i]));
          bv[i] = take ? ov : bv[i];
          bk[i] = take ? ok : bk[i];
        }
      }
      // lane writes 64B of row (lane>>2); its group (lane>>4) holds that row
      int j = (lane >> 2) & 3;
      int k01 = (j & 1) ? bk[1] : bk[0];
      int k23 = (j & 1) ? bk[3] : bk[2];
      int kk = (j & 2) ? k23 : k01;
      int r = row0 + a * 16 + (lane >> 2);
      const float4* src = (const float4*)(emb + kk * D + (lane & 3) * 16);
      float4* dst = (float4*)(out + (size_t)r * D + (lane & 3) * 16);
#pragma unroll
      for (int s = 0; s < 4; ++s) dst[s] = src[s];
    }
  }
}

extern "C" void kernel_launch(void* const* d_in, const int* in_sizes, int n_in,
                              void* d_out, int out_size, void* d_ws, size_t ws_size,
                              hipStream_t stream) {
  const float* x = (const float*)d_in[0];
  const float* emb = (const float*)d_in[1];
  float* out = (float*)d_out;
  int nrows = in_sizes[0] / D; // 262144
  vq_mfma<<<256, BLOCK, 0, stream>>>(x, emb, out, nrows);
}